// Round 5
// baseline (417.291 us; speedup 1.0000x reference)
//
#include <hip/hip_runtime.h>
#include <hip/hip_bf16.h>

typedef __attribute__((ext_vector_type(8))) short short8;
typedef __attribute__((ext_vector_type(4))) float floatx4;
typedef unsigned short u16;

#define NB 32
#define NN 1536
#define NM 80
#define NH 8
#define NC 64
#define NINNER 512
#define NQD 320
#define NKD 768

__device__ __forceinline__ float bf2f(u16 u) {
    union { unsigned i; float f; } x; x.i = ((unsigned)u) << 16; return x.f;
}
__device__ __forceinline__ u16 f2bf(float f) {
    unsigned u = __float_as_uint(f);
    unsigned r = (u + 0x7FFFu + ((u >> 16) & 1u)) >> 16;  // RNE
    return (u16)r;
}
__device__ __forceinline__ short8 cvt8(const float* __restrict__ p) {
    float4 a = ((const float4*)p)[0];
    float4 b = ((const float4*)p)[1];
    short8 r;
    r[0] = (short)f2bf(a.x); r[1] = (short)f2bf(a.y);
    r[2] = (short)f2bf(a.z); r[3] = (short)f2bf(a.w);
    r[4] = (short)f2bf(b.x); r[5] = (short)f2bf(b.y);
    r[6] = (short)f2bf(b.z); r[7] = (short)f2bf(b.w);
    return r;
}
__device__ __forceinline__ void gload16(const u16* g, u16* l) {
    __builtin_amdgcn_global_load_lds(
        (const __attribute__((address_space(1))) unsigned int*)g,
        (__attribute__((address_space(3))) unsigned int*)l, 16, 0, 0);
}

// ---------------------------------------------------------------------------
// Input dtype detect: flag=1 means float tensors are f32.
// ---------------------------------------------------------------------------
__global__ __launch_bounds__(256) void detect_dtype(const u16* __restrict__ x,
                                                    int* __restrict__ flag) {
    __shared__ int cnt;
    if (threadIdx.x == 0) cnt = 0;
    __syncthreads();
    int c = 0;
    for (int i = threadIdx.x; i < 8192; i += 256) {
        unsigned e = (x[i] >> 7) & 0xFF;
        if (e >= 0xA0) c++;
    }
    atomicAdd(&cnt, c);
    __syncthreads();
    if (threadIdx.x == 0) *flag = (cnt > 64) ? 1 : 0;
}

// ---------------------------------------------------------------------------
// Mask prep (self-detecting storage dtype) -> f32 additive bias per (b,m).
// ---------------------------------------------------------------------------
__global__ __launch_bounds__(256) void mask_prep(const unsigned char* __restrict__ raw,
                                                 float* __restrict__ maskbias) {
    __shared__ int c_bf, c_f32, c_u8;
    if (threadIdx.x == 0) { c_bf = 0; c_f32 = 0; c_u8 = 0; }
    __syncthreads();
    for (int i = threadIdx.x; i < NB * NM; i += 256) {
        unsigned char v = raw[i];
        if (v == 0x3F && (i & 3) == 1) atomicAdd(&c_bf, 1);
        if (v == 0x3F && (i & 3) == 3) atomicAdd(&c_f32, 1);
        if (v != 0 && (i & 3) != 0) atomicAdd(&c_u8, 1);
    }
    __syncthreads();
    int md;
    if (c_bf > 0) md = 2;
    else if (c_f32 > 0) md = 3;
    else if (c_u8 > 0) md = 1;
    else md = 0;
    for (int i = threadIdx.x; i < NB * NM; i += 256) {
        bool on;
        if (md == 2) on = ((const u16*)raw)[i] != 0;
        else if (md == 3) on = ((const float*)raw)[i] != 0.0f;
        else if (md == 1) on = raw[i] != 0;
        else on = ((const int*)raw)[i] != 0;
        maskbias[i] = on ? 0.0f : -3.4028234663852886e38f;
    }
}

// ---------------------------------------------------------------------------
// Batched f32->bf16 conversion for weight matrices.
// ---------------------------------------------------------------------------
struct ConvSeg { const void* src; u16* dst; int nblk; };
struct ConvArgs { ConvSeg s[3]; };

__global__ __launch_bounds__(256) void conv_batch(ConvArgs a, const int* __restrict__ flag) {
    const int f = *flag;
    int b = blockIdx.x, seg = 0;
    while (seg < 3 && b >= a.s[seg].nblk) { b -= a.s[seg].nblk; seg++; }
    if (seg >= 3) return;
    const long idx = (long)b * 2048 + threadIdx.x * 8;
    u16* dst = a.s[seg].dst;
    if (f) *(short8*)(dst + idx) = cvt8((const float*)a.s[seg].src + idx);
    else   *(short8*)(dst + idx) = *(const short8*)((const u16*)a.s[seg].src + idx);
}

// Wo (320x512) -> padded bf16 (384x512), zero rows 320..383.  96 blocks.
__global__ __launch_bounds__(256) void conv_wo(const void* __restrict__ src,
                                               u16* __restrict__ dst,
                                               const int* __restrict__ flag) {
    const int f = *flag;
    const long idx = ((long)blockIdx.x * 256 + threadIdx.x) * 8;
    const int row = (int)(idx >> 9);
    if (row < NQD) {
        if (f) *(short8*)(dst + idx) = cvt8((const float*)src + idx);
        else   *(short8*)(dst + idx) = *(const short8*)((const u16*)src + idx);
    } else {
        *(short8*)(dst + idx) = (short8)0;
    }
}

// ---------------------------------------------------------------------------
// m97-style bf16 MFMA GEMM. 128x128 tile, BK=32, 4 waves 2x2 each 64x64.
// A: f32-converted in staging when (A_DYN && flag), else bf16. B: bf16 via
// global_load_lds w=16, XOR chunk swizzle. OPROJ: cols<Ncols predicated,
// +bias(bo), out f32/bf16 per flag -> outp. Else: bf16 -> C.
// ---------------------------------------------------------------------------
template <bool A_DYN, bool OPROJ, bool DUAL>
__global__ __launch_bounds__(256) void gemm128(const void* __restrict__ A,
                                               const u16* __restrict__ B,
                                               u16* __restrict__ C,
                                               const void* __restrict__ A2,
                                               const u16* __restrict__ B2,
                                               u16* __restrict__ C2,
                                               const void* __restrict__ bias,
                                               void* __restrict__ outp,
                                               int Ncols, int K,
                                               const int* __restrict__ flag) {
    __shared__ __align__(16) u16 As[128 * 32];
    __shared__ __align__(16) u16 Bs[128 * 32];
    if (DUAL && blockIdx.z) { A = A2; B = B2; C = C2; }
    const int f = *flag;
    const int tid = threadIdx.x;
    const int wave = tid >> 6, lane = tid & 63;
    const int l16 = lane & 15, quad = lane >> 4;
    const int wr = wave >> 1, wc = wave & 1;
    const int bm0 = blockIdx.x * 128, bn0 = blockIdx.y * 128;

    const int r0 = tid >> 2, c0 = tid & 3;
    const int sc = c0 ^ ((r0 >> 1) & 3);
    const u16* Bg = B + (size_t)(bn0 + r0) * K + sc * 8;
    u16* BsW = Bs + wave * 512;
    u16* AsD = As + wave * 512 + (size_t)lane * 8;
    const size_t aoff = (size_t)(bm0 + r0) * K + sc * 8;

    const int swz = (l16 >> 1) & 3;
    floatx4 acc[4][4];
#pragma unroll
    for (int i = 0; i < 4; ++i)
#pragma unroll
        for (int n = 0; n < 4; ++n) acc[i][n] = (floatx4)0.0f;

    for (int kk = 0; kk < K; kk += 32) {
        __syncthreads();
#pragma unroll
        for (int j = 0; j < 2; ++j) {
            short8 av;
            if (A_DYN && f) av = cvt8((const float*)A + aoff + (size_t)(j * 64) * K + kk);
            else            av = *(const short8*)((const u16*)A + aoff + (size_t)(j * 64) * K + kk);
            *(short8*)(AsD + j * 2048) = av;
            gload16(Bg + (size_t)(j * 64) * K + kk, BsW + j * 2048);
        }
        __syncthreads();
        short8 af[4], bf[4];
#pragma unroll
        for (int i = 0; i < 4; ++i)
            af[i] = *(const short8*)&As[(wr * 64 + i * 16 + l16) * 32 + ((quad ^ swz) * 8)];
#pragma unroll
        for (int n = 0; n < 4; ++n)
            bf[n] = *(const short8*)&Bs[(wc * 64 + n * 16 + l16) * 32 + ((quad ^ swz) * 8)];
#pragma unroll
        for (int i = 0; i < 4; ++i)
#pragma unroll
            for (int n = 0; n < 4; ++n)
                acc[i][n] = __builtin_amdgcn_mfma_f32_16x16x32_bf16(af[i], bf[n], acc[i][n], 0, 0, 0);
    }

#pragma unroll
    for (int n = 0; n < 4; ++n) {
        const int col = bn0 + wc * 64 + n * 16 + l16;
        if (OPROJ) {
            if (col < Ncols) {
                const float badd = f ? ((const float*)bias)[col] : bf2f(((const u16*)bias)[col]);
#pragma unroll
                for (int i = 0; i < 4; ++i)
#pragma unroll
                    for (int r = 0; r < 4; ++r) {
                        const int row = bm0 + wr * 64 + i * 16 + quad * 4 + r;
                        const float val = acc[i][n][r] + badd;
                        if (f) ((float*)outp)[(size_t)row * Ncols + col] = val;
                        else   ((u16*)outp)[(size_t)row * Ncols + col] = f2bf(val);
                    }
            }
        } else {
#pragma unroll
            for (int i = 0; i < 4; ++i)
#pragma unroll
                for (int r = 0; r < 4; ++r) {
                    const int row = bm0 + wr * 64 + i * 16 + quad * 4 + r;
                    C[(size_t)row * Ncols + col] = f2bf(acc[i][n][r]);
                }
        }
    }
}

// ---------------------------------------------------------------------------
// V transpose into (b,h,c,m) with K padded 80->96 (zeros). Internal bf16.
// ---------------------------------------------------------------------------
__global__ __launch_bounds__(256) void transpose_v(const u16* __restrict__ v,
                                                   u16* __restrict__ vT) {
    int b = blockIdx.x >> 3, h = blockIdx.x & 7;
    const u16* src = v + (size_t)b * NM * NINNER + h * NC;
    u16* o = vT + (size_t)(b * NH + h) * NC * 96;
    for (int idx = threadIdx.x; idx < NM * NC; idx += 256) {
        int m = idx >> 6, c = idx & 63;
        o[c * 96 + m] = src[(size_t)m * NINNER + c];
    }
    for (int idx = threadIdx.x; idx < NC * 16; idx += 256) {
        int c = idx >> 4, m = 80 + (idx & 15);
        o[c * 96 + m] = 0;
    }
}

// ---------------------------------------------------------------------------
// kq[b,h,m,d] = sum_c k[b,m,h*64+c] * Wq[h*64+c,d]  (replaces Q-projection:
// sim = x @ kq^T). One block per (b,h); Wq_h^T staged in LDS.
// ---------------------------------------------------------------------------
__global__ __launch_bounds__(256) void kq_gemm(const u16* __restrict__ k,
                                               const u16* __restrict__ Wq,
                                               u16* __restrict__ kq) {
    __shared__ __align__(16) u16 WqT[NQD * 72];
    const int b = blockIdx.x >> 3, h = blockIdx.x & 7;
    const int tid = threadIdx.x;
    const int lane = tid & 63, wave = tid >> 6;
    const int l16 = lane & 15, quad = lane >> 4;
    for (int i = tid; i < NC * NQD; i += 256) {
        const int c = i / NQD, d = i % NQD;
        WqT[d * 72 + c] = Wq[(size_t)(h * NC + c) * NQD + d];
    }
    __syncthreads();
#pragma unroll
    for (int dd = 0; dd < 5; ++dd) {
        const int dt = wave * 5 + dd;
#pragma unroll
        for (int mt = 0; mt < 5; ++mt) {
            floatx4 acc = (floatx4)0.0f;
#pragma unroll
            for (int kk = 0; kk < 2; ++kk) {
                short8 a = *(const short8*)(k + (size_t)(b * NM + mt * 16 + l16) * NINNER + h * NC + kk * 32 + quad * 8);
                short8 bf = *(const short8*)&WqT[(dt * 16 + l16) * 72 + kk * 32 + quad * 8];
                acc = __builtin_amdgcn_mfma_f32_16x16x32_bf16(a, bf, acc, 0, 0, 0);
            }
#pragma unroll
            for (int r = 0; r < 4; ++r) {
                const int m = mt * 16 + quad * 4 + r;
                kq[((size_t)(b * NH + h) * NM + m) * NQD + dt * 16 + l16] = f2bf(acc[r]);
            }
        }
    }
}

// ---------------------------------------------------------------------------
// Attention via kq: block (64 rows, h, b). sim = x_bf @ kq_h^T (K=320),
// +scale/mask/box/road, softmax over M=80, out = P @ V -> ao (bf16).
// kq_h staged to LDS (global_load_lds, XOR chunk swizzle); x read as f32
// with cvt in the A-frag load (per flag).
// ---------------------------------------------------------------------------
__global__ __launch_bounds__(256) void attn_kq(const void* __restrict__ x,
                                               const u16* __restrict__ kq,
                                               const u16* __restrict__ vT,
                                               const float* __restrict__ maskbias,
                                               const void* __restrict__ box,
                                               const void* __restrict__ road,
                                               u16* __restrict__ attno,
                                               const int* __restrict__ flag) {
    const int f = *flag;
    const int n0 = blockIdx.x * 64;
    const int h = blockIdx.y;
    const int b = blockIdx.z;
    const int tid = threadIdx.x;
    const int wave = tid >> 6, lane = tid & 63;
    const int l16 = lane & 15, quad = lane >> 4;

    __shared__ __align__(16) u16 kq_s[25600];     // 10 slices x 80 rows x 32, swizzled
    __shared__ __align__(16) u16 p_lds[64][104];

    // zero P pad cols 80..95 (each wave its own rows)
    {
        const int row = 16 * wave + (lane >> 2);
        const int col = 80 + (lane & 3) * 4;
        ushort4 z; z.x = 0; z.y = 0; z.z = 0; z.w = 0;
        *(ushort4*)&p_lds[row][col] = z;
    }

    // stage kq_h (80 x 320) into swizzled slices
    {
        const int r0 = tid >> 2, c0 = tid & 3;
        const int sc = c0 ^ ((r0 >> 1) & 3);
        const u16* g = kq + ((size_t)(b * NH + h) * NM + r0) * NQD + sc * 8;
#pragma unroll
        for (int s = 0; s < 10; ++s)
            gload16(g + s * 32, kq_s + s * 2560 + wave * 512);
        if (tid < 64) {
            const u16* g2 = g + (size_t)64 * NQD;
#pragma unroll
            for (int s = 0; s < 10; ++s)
                gload16(g2 + s * 32, kq_s + s * 2560 + 2048);
        }
    }

    // hoisted bias: add[mt][r] = maskbias + 5*box + 5*road
    float add[5][4];
#pragma unroll
    for (int r = 0; r < 4; ++r) {
        const int n = n0 + 16 * wave + quad * 4 + r;
        const size_t ridx = (size_t)b * NN + n;
        const float roadv = 5.0f * (f ? ((const float*)road)[ridx]
                                      : bf2f(((const u16*)road)[ridx]));
#pragma unroll
        for (int mt = 0; mt < 5; ++mt) {
            const int m = mt * 16 + l16;
            const float boxv = 5.0f * (f ? ((const float*)box)[ridx * NM + m]
                                         : bf2f(((const u16*)box)[ridx * NM + m]));
            add[mt][r] = maskbias[b * NM + m] + boxv + roadv;
        }
    }

    __syncthreads();  // kq_s landed (barrier drains vmcnt), p pad written

    // sim = x_tile @ kq_h^T, K = 320
    floatx4 s[5];
#pragma unroll
    for (int i = 0; i < 5; ++i) s[i] = (floatx4)0.0f;
    const size_t xrow = (size_t)(b * NN + n0 + 16 * wave + l16) * NQD;
    const int swz = (l16 >> 1) & 3;
#pragma unroll
    for (int t = 0; t < 10; ++t) {
        short8 a;
        if (f) a = cvt8((const float*)x + xrow + t * 32 + quad * 8);
        else   a = *(const short8*)((const u16*)x + xrow + t * 32 + quad * 8);
#pragma unroll
        for (int mt = 0; mt < 5; ++mt) {
            short8 bfr = *(const short8*)&kq_s[t * 2560 + (mt * 16 + l16) * 32 + ((quad ^ swz) * 8)];
            s[mt] = __builtin_amdgcn_mfma_f32_16x16x32_bf16(a, bfr, s[mt], 0, 0, 0);
        }
    }

    // scale + bias (in place), then softmax over M=80
    float inv[4];
#pragma unroll
    for (int r = 0; r < 4; ++r) {
#pragma unroll
        for (int mt = 0; mt < 5; ++mt)
            s[mt][r] = s[mt][r] * 0.125f + add[mt][r];
        float mx = s[0][r];
#pragma unroll
        for (int mt = 1; mt < 5; ++mt) mx = fmaxf(mx, s[mt][r]);
#pragma unroll
        for (int off = 1; off < 16; off <<= 1) mx = fmaxf(mx, __shfl_xor(mx, off, 16));
        float sum = 0.0f;
#pragma unroll
        for (int mt = 0; mt < 5; ++mt) {
            const float p = __expf(s[mt][r] - mx);
            s[mt][r] = p;
            sum += p;
        }
#pragma unroll
        for (int off = 1; off < 16; off <<= 1) sum += __shfl_xor(sum, off, 16);
        inv[r] = 1.0f / sum;
    }

    // P -> LDS (own rows; wave-local, no barrier)
#pragma unroll
    for (int r = 0; r < 4; ++r) {
        const int lr = 16 * wave + quad * 4 + r;
#pragma unroll
        for (int mt = 0; mt < 5; ++mt) p_lds[lr][mt * 16 + l16] = f2bf(s[mt][r]);
    }

    // out = P @ V
    floatx4 o[4];
#pragma unroll
    for (int i = 0; i < 4; ++i) o[i] = (floatx4)0.0f;
    const u16* vbase = vT + (size_t)(b * NH + h) * NC * 96;
#pragma unroll
    for (int kk = 0; kk < 96; kk += 32) {
        short8 a = *(const short8*)&p_lds[16 * wave + l16][kk + quad * 8];
#pragma unroll
        for (int nt = 0; nt < 4; ++nt) {
            short8 bfr = *(const short8*)(vbase + (size_t)(nt * 16 + l16) * 96 + kk + quad * 8);
            o[nt] = __builtin_amdgcn_mfma_f32_16x16x32_bf16(a, bfr, o[nt], 0, 0, 0);
        }
    }

#pragma unroll
    for (int nt = 0; nt < 4; ++nt) {
#pragma unroll
        for (int r = 0; r < 4; ++r) {
            const int n = n0 + 16 * wave + quad * 4 + r;
            attno[((size_t)b * NN + n) * NINNER + h * NC + nt * 16 + l16] = f2bf(o[nt][r] * inv[r]);
        }
    }
}

extern "C" void kernel_launch(void* const* d_in, const int* in_sizes, int n_in,
                              void* d_out, int out_size, void* d_ws, size_t ws_size,
                              hipStream_t stream) {
    (void)in_sizes; (void)n_in; (void)out_size; (void)ws_size;
    const void* x    = d_in[0];
    const void* key  = d_in[1];
    const void* val  = d_in[2];
    const unsigned char* mask = (const unsigned char*)d_in[3];
    const void* box  = d_in[4];
    const void* road = d_in[5];
    const void* Wq   = d_in[6];
    const void* Wk   = d_in[7];
    const void* Wv   = d_in[8];
    const void* Wo   = d_in[9];
    const void* bo   = d_in[10];

    char* ws = (char*)d_ws;
    size_t off = 0;
    auto carve = [&](size_t bytes) {
        char* p = ws + off;
        off += (bytes + 255) & ~(size_t)255;
        return p;
    };
    int* flag   = (int*)carve(256);
    u16* k_ws   = (u16*)carve((size_t)NB * NM * NINNER * 2);    // 2.6 MB
    u16* v_ws   = (u16*)carve((size_t)NB * NM * NINNER * 2);    // 2.6 MB
    u16* vT_ws  = (u16*)carve((size_t)NB * NH * NC * 96 * 2);   // 3.1 MB
    u16* kq_ws  = (u16*)carve((size_t)NB * NH * NM * NQD * 2);  // 13.1 MB
    u16* ao_ws  = (u16*)carve((size_t)NB * NN * NINNER * 2);    // 50.3 MB
    u16* Wq_bf  = (u16*)carve((size_t)NINNER * NQD * 2);
    u16* Wk_bf  = (u16*)carve((size_t)NINNER * NKD * 2);
    u16* Wv_bf  = (u16*)carve((size_t)NINNER * NKD * 2);
    u16* WoP_bf = (u16*)carve((size_t)384 * NINNER * 2);
    float* mb   = (float*)carve((size_t)NB * NM * 4);

    detect_dtype<<<1, 256, 0, stream>>>((const u16*)x, flag);
    mask_prep<<<1, 256, 0, stream>>>(mask, mb);

    ConvArgs ca;
    ca.s[0] = { Wq, Wq_bf, (int)((size_t)NINNER * NQD / 2048) };  // 80
    ca.s[1] = { Wk, Wk_bf, (int)((size_t)NINNER * NKD / 2048) };  // 192
    ca.s[2] = { Wv, Wv_bf, (int)((size_t)NINNER * NKD / 2048) };  // 192
    conv_batch<<<464, 256, 0, stream>>>(ca, flag);
    conv_wo<<<96, 256, 0, stream>>>(Wo, WoP_bf, flag);

    // k/v = {key,value} @ {Wk,Wv}^T : (2560 x 768) @ (512 x 768)^T, dual
    gemm128<true, false, true><<<dim3(NB * NM / 128, NINNER / 128, 2), 256, 0, stream>>>(
        key, Wk_bf, k_ws, val, Wv_bf, v_ws, nullptr, nullptr, NINNER, NKD, flag);
    transpose_v<<<NB * NH, 256, 0, stream>>>(v_ws, vT_ws);
    // kq = k @ Wq (per head) : replaces the entire Q projection
    kq_gemm<<<NB * NH, 256, 0, stream>>>(k_ws, Wq_bf, kq_ws);
    // attention: sim = x @ kq^T, softmax, P @ V -> ao
    attn_kq<<<dim3(NN / 64, NH, NB), 256, 0, stream>>>(
        x, kq_ws, vT_ws, mb, box, road, ao_ws, flag);
    // out = ao @ WoP^T + bo : (49152 x 512) @ (384 x 512)^T, cols<320
    gemm128<false, true, false><<<dim3(NB * NN / 128, 3), 256, 0, stream>>>(
        ao_ws, WoP_bf, nullptr, nullptr, nullptr, nullptr, bo, d_out, NQD, NINNER, flag);
}